// Round 4
// baseline (46528.110 us; speedup 1.0000x reference)
//
#include <hip/hip_runtime.h>
#include <stdint.h>

typedef unsigned short u16;
typedef unsigned long long u64;
typedef __bf16 bf16x8 __attribute__((ext_vector_type(8)));
typedef float f32x4 __attribute__((ext_vector_type(4)));
typedef u64 u64x2 __attribute__((ext_vector_type(2)));

#define S_LEN 288
#define T_LEN 144
#define HID   512
#define BATCH 2048
#define NBLK  512
#define HBUF  ((size_t)BATCH * HID)

__device__ __forceinline__ u16 f2bf(float f){
  unsigned u = __builtin_bit_cast(unsigned, f);
  u = u + 0x7fffu + ((u >> 16) & 1u);
  return (u16)(u >> 16);
}
__device__ __forceinline__ float sigf(float x){ return 1.0f/(1.0f + __expf(-x)); }
__device__ __forceinline__ float tanh_f(float x){ return 1.0f - 2.0f/(1.0f + __expf(2.0f*x)); }

// agent-scope (sc1): bypass per-XCD L2, coherent at memory-side L3 (replay-proven in R2)
__device__ __forceinline__ u64 aload64(const u16* p){
  return __hip_atomic_load((const u64*)p, __ATOMIC_RELAXED, __HIP_MEMORY_SCOPE_AGENT);
}
__device__ __forceinline__ float aloadf(const float* p){
  return __hip_atomic_load(p, __ATOMIC_RELAXED, __HIP_MEMORY_SCOPE_AGENT);
}
__device__ __forceinline__ void astore64(void* p, u64 v){
  __hip_atomic_store((u64*)p, v, __ATOMIC_RELAXED, __HIP_MEMORY_SCOPE_AGENT);
}
__device__ __forceinline__ void astoref(float* p, float v){
  __hip_atomic_store(p, v, __ATOMIC_RELAXED, __HIP_MEMORY_SCOPE_AGENT);
}

struct Params {
  const float* x;
  const u16 *We0, *We1i, *We1h, *Wd0, *Wd1i, *Wd1h;
  const float *be0, *be1, *bd0, *bd1, *wxe, *wxd, *fcW, *fcbp;
  u16 *h0buf, *h1buf;
  float* preds;
  unsigned* gcnt;
  float* out;
};

// ---------------- prep kernels ----------------
// orig row = gate*512 + hu  ->  new row = (hu>>3)*32 + gate*8 + (hu&7)
// => each 32-row band holds all 4 gates of 8 hidden units (one wave's n-slice)
__global__ void k_reorder_w(const float* __restrict__ src, u16* __restrict__ dst){
  int idx  = blockIdx.x * 256 + threadIdx.x;       // 2048*512 threads
  int k    = idx & (HID-1);
  int orig = idx >> 9;
  int gate = orig >> 9, hu = orig & (HID-1);
  int nr   = ((hu >> 3) << 5) + (gate << 3) + (hu & 7);
  dst[(size_t)nr * HID + k] = f2bf(src[idx]);
}

__global__ void k_prep_small(const float* __restrict__ bih, const float* __restrict__ bhh,
                             float* __restrict__ bdst,
                             const float* __restrict__ wcol, float* __restrict__ wdst){
  int orig = blockIdx.x * 256 + threadIdx.x;       // 0..2047
  int gate = orig >> 9, hu = orig & (HID-1);
  int nr   = ((hu >> 3) << 5) + (gate << 3) + (hu & 7);
  bdst[nr] = bih[orig] + bhh[orig];
  if (wcol) wdst[nr] = wcol[orig];
}

// ---------------- m-group barrier (16 blocks, own cacheline, R2-proven shape) ----------------
__device__ __forceinline__ void gbar(unsigned* cnt, unsigned& epoch){
  __syncthreads();
  ++epoch;
  if (threadIdx.x == 0){
    __hip_atomic_fetch_add(cnt, 1u, __ATOMIC_RELEASE, __HIP_MEMORY_SCOPE_AGENT);
    const unsigned tgt = epoch * 16u;
    while (__hip_atomic_load(cnt, __ATOMIC_RELAXED, __HIP_MEMORY_SCOPE_AGENT) < tgt)
      __builtin_amdgcn_s_sleep(1);
  }
  __syncthreads();
}

// ---------------- register-fragment K=512 GEMM (wave tile 64m x 32n) ----------------
// A (h) per-lane sc1 loads; B (weights) plain int4 loads (L2-resident, read-only).
// Register double-buffer: chunk c+1 loads issued before chunk c MFMAs.
template<bool DUAL>
__device__ __forceinline__ void gemm_reg(
    const u16* __restrict__ Ag, const u16* __restrict__ Bg, const u16* __restrict__ B2g,
    f32x4 (&acc)[4][2], f32x4 (&acc2)[4][2],
    const int (&aoff)[4], const int (&boff)[2])
{
  u64 a0[4], a1[4], na0[4], na1[4];
  int4 bc[2], b2c[2], nb[2], nb2[2];
  #pragma unroll
  for (int mf = 0; mf < 4; ++mf){
    a0[mf] = aload64(Ag + aoff[mf]);
    a1[mf] = aload64(Ag + aoff[mf] + 4);
  }
  #pragma unroll
  for (int nf = 0; nf < 2; ++nf){
    bc[nf] = *(const int4*)(Bg + boff[nf]);
    if (DUAL) b2c[nf] = *(const int4*)(B2g + boff[nf]);
  }
  #pragma unroll
  for (int c = 0; c < 16; ++c){
    if (c < 15){
      const int ko = (c+1)*32;
      #pragma unroll
      for (int mf = 0; mf < 4; ++mf){
        na0[mf] = aload64(Ag + aoff[mf] + ko);
        na1[mf] = aload64(Ag + aoff[mf] + ko + 4);
      }
      #pragma unroll
      for (int nf = 0; nf < 2; ++nf){
        nb[nf] = *(const int4*)(Bg + boff[nf] + ko);
        if (DUAL) nb2[nf] = *(const int4*)(B2g + boff[nf] + ko);
      }
    }
    bf16x8 af[4], bf[2], b2f[2];
    #pragma unroll
    for (int mf = 0; mf < 4; ++mf){
      u64x2 t; t.x = a0[mf]; t.y = a1[mf];
      af[mf] = __builtin_bit_cast(bf16x8, t);
    }
    #pragma unroll
    for (int nf = 0; nf < 2; ++nf){
      bf[nf] = __builtin_bit_cast(bf16x8, bc[nf]);
      if (DUAL) b2f[nf] = __builtin_bit_cast(bf16x8, b2c[nf]);
    }
    #pragma unroll
    for (int mf = 0; mf < 4; ++mf){
      #pragma unroll
      for (int nf = 0; nf < 2; ++nf){
        acc[mf][nf] = __builtin_amdgcn_mfma_f32_16x16x32_bf16(af[mf], bf[nf], acc[mf][nf], 0, 0, 0);
        if (DUAL)
          acc2[mf][nf] = __builtin_amdgcn_mfma_f32_16x16x32_bf16(af[mf], b2f[nf], acc2[mf][nf], 0, 0, 0);
      }
    }
    if (c < 15){
      #pragma unroll
      for (int mf = 0; mf < 4; ++mf){ a0[mf] = na0[mf]; a1[mf] = na1[mf]; }
      #pragma unroll
      for (int nf = 0; nf < 2; ++nf){ bc[nf] = nb[nf]; if (DUAL) b2c[nf] = nb2[nf]; }
    }
  }
}

// ---------------- LSTM cell epilogue ----------------
// C-layout: col=l15 (n-row = wave*32 + nf*16 + l15), row = quad*4+r + mf*16 (batch-local).
// n-row -> gate (nf*2 + (l15>>3)) of hu = n_blk*32 + wave*8 + (l15&7); partner lane = l15^8.
template<bool X0, bool PRED>
__device__ __forceinline__ void cell_epi(
    f32x4 (&acc)[4][2], float* cst, const float* bv, const float* wxv,
    const float* xin, u16* scr,
    int wave, int quad, int l15, int m0,
    float fcWv, float* predrow)
{
  const int hilane = l15 >> 3, hu7 = l15 & 7;
  #pragma unroll
  for (int mf = 0; mf < 4; ++mf){
    #pragma unroll
    for (int r = 0; r < 4; ++r){
      const float a0 = acc[mf][0][r], a1 = acc[mf][1][r];
      const float p0 = __shfl_xor(a0, 8), p1 = __shfl_xor(a1, 8);
      float gi = (hilane ? p0 : a0) + bv[0];
      float gf = (hilane ? a0 : p0) + bv[1];
      float gg = (hilane ? p1 : a1) + bv[2];
      float go = (hilane ? a1 : p1) + bv[3];
      if (X0){
        const float xt = xin[mf*4 + r];
        gi += xt*wxv[0]; gf += xt*wxv[1]; gg += xt*wxv[2]; go += xt*wxv[3];
      }
      const float c = sigf(gf)*cst[mf*4+r] + sigf(gi)*tanh_f(gg);
      cst[mf*4+r] = c;
      const float h = sigf(go)*tanh_f(c);
      if (!hilane) scr[(mf*16 + quad*4 + r)*40 + wave*8 + hu7] = f2bf(h);
      if (PRED){
        float v = hilane ? 0.f : h*fcWv;
        v += __shfl_xor(v, 1); v += __shfl_xor(v, 2);
        v += __shfl_xor(v, 4); v += __shfl_xor(v, 8);
        if (l15 == 0) atomicAdd(&predrow[m0 + mf*16 + quad*4 + r], v);
      }
    }
  }
}

// drain scratch -> global h (agent-scope sc1, 16B/thread)
__device__ __forceinline__ void drain_h(const u16* scr, u16* hdst, int m0, int col0, int tid){
  __syncthreads();
  const int row = tid >> 2, q = tid & 3;
  const u64* s = (const u64*)(scr + row*40 + q*8);
  const u64 lo = s[0], hi = s[1];
  u64* d = (u64*)(hdst + (size_t)(m0+row)*HID + col0 + q*8);
  astore64(d, lo);
  astore64(d+1, hi);
  __syncthreads();
}

// ---------------- persistent main kernel ----------------
__global__ __launch_bounds__(256, 2) void lstm_main(Params P){
  const int tid   = threadIdx.x;
  const int bx    = blockIdx.x;
  const int n_blk = (bx & 7)*2 + ((bx >> 3) & 1);   // same-n per XCD -> weights L2-resident
  const int m_blk = bx >> 4;                        // m-group = 16 consecutive bx (independent!)
  const int m0 = m_blk * 64, n0 = n_blk * 128;
  const int wave = tid >> 6, lane = tid & 63;
  const int l15 = lane & 15, quad = lane >> 4;
  const int hu = n_blk*32 + wave*8 + (l15 & 7);
  const int col0 = n_blk*32;

  __shared__ u16 scr[64*40];    // 5 KB h-scratch

  unsigned* cnt = P.gcnt + m_blk*32;   // 128B-spaced per-group line

  // per-lane fragment offsets
  int aoff[4], boff[2];
  #pragma unroll
  for (int mf = 0; mf < 4; ++mf) aoff[mf] = (mf*16 + l15)*HID + quad*8;
  #pragma unroll
  for (int nf = 0; nf < 2; ++nf) boff[nf] = (wave*32 + nf*16 + l15)*HID + quad*8;

  float c0s[16], c1s[16];
  #pragma unroll
  for (int i = 0; i < 16; ++i){ c0s[i] = 0.f; c1s[i] = 0.f; }

  float be0v[4], be1v[4], bd0v[4], bd1v[4], wxev[4], wxdv[4];
  #pragma unroll
  for (int g = 0; g < 4; ++g){
    const int col = (n_blk*4 + wave)*32 + g*8 + (l15 & 7);
    be0v[g] = P.be0[col]; be1v[g] = P.be1[col];
    bd0v[g] = P.bd0[col]; bd1v[g] = P.bd1[col];
    wxev[g] = P.wxe[col]; wxdv[g] = P.wxd[col];
  }
  const float fcWv = P.fcW[hu];
  const float fcb  = P.fcbp[0];

  const size_t nb = (size_t)n0 * HID;
  const u16* We0b  = P.We0  + nb;
  const u16* We1ib = P.We1i + nb;
  const u16* We1hb = P.We1h + nb;
  const u16* Wd0b  = P.Wd0  + nb;
  const u16* Wd1ib = P.Wd1i + nb;
  const u16* Wd1hb = P.Wd1h + nb;
  const size_t mb = (size_t)m0 * HID;
  u16* h0b[2] = { P.h0buf, P.h0buf + HBUF };
  u16* h1b[2] = { P.h1buf, P.h1buf + HBUF };

  unsigned epoch = 0;

  // ===== encoder: phase p runs layer0(t=p) and layer1(t=p-1) =====
  for (int p = 0; p <= S_LEN; ++p){
    float xin[16];
    if (p < S_LEN){
      #pragma unroll
      for (int mf = 0; mf < 4; ++mf)
        #pragma unroll
        for (int r = 0; r < 4; ++r)
          xin[mf*4+r] = P.x[(size_t)(m0 + mf*16 + quad*4 + r)*S_LEN + p];
    }
    f32x4 acc0[4][2], acc1[4][2];
    #pragma unroll
    for (int i = 0; i < 4; ++i)
      #pragma unroll
      for (int j = 0; j < 2; ++j){ acc0[i][j] = f32x4{0.f,0.f,0.f,0.f}; acc1[i][j] = f32x4{0.f,0.f,0.f,0.f}; }

    // shared A = h0(p-1): layer0 recurrence + layer1 input GEMM (dual B)
    gemm_reg<true >(h0b[p & 1] + mb, We0b, We1ib, acc0, acc1, aoff, boff);
    // layer1 hidden GEMM: A = h1(p-2)
    gemm_reg<false>(h1b[(p+1) & 1] + mb, We1hb, We1hb, acc1, acc1, aoff, boff);

    if (p < S_LEN){
      cell_epi<true,false>(acc0, c0s, be0v, wxev, xin, scr, wave, quad, l15, m0, 0.f, nullptr);
      drain_h(scr, h0b[(p+1) & 1], m0, col0, tid);
    }
    if (p >= 1){
      cell_epi<false,false>(acc1, c1s, be1v, nullptr, nullptr, scr, wave, quad, l15, m0, 0.f, nullptr);
      drain_h(scr, h1b[p & 1], m0, col0, tid);
    }
    gbar(cnt, epoch);
  }

  // ===== decoder: 2 phases per step (pred feedback) =====
  for (int t = 0; t < T_LEN; ++t){
    if (t > 0 && n_blk == 0 && tid < 64){
      const float pv = aloadf(&P.preds[((t+1) & 1)*BATCH + m0 + tid]);
      P.out[(size_t)(m0 + tid)*T_LEN + (t-1)] = pv + fcb;
    }
    { // phase A: dec layer0
      float xin[16];
      #pragma unroll
      for (int mf = 0; mf < 4; ++mf)
        #pragma unroll
        for (int r = 0; r < 4; ++r){
          const int b = m0 + mf*16 + quad*4 + r;
          xin[mf*4+r] = (t == 0) ? P.x[(size_t)b*S_LEN + (S_LEN-1)]
                                 : (aloadf(&P.preds[((t+1) & 1)*BATCH + b]) + fcb);
        }
      f32x4 acc0[4][2];
      #pragma unroll
      for (int i = 0; i < 4; ++i)
        #pragma unroll
        for (int j = 0; j < 2; ++j) acc0[i][j] = f32x4{0.f,0.f,0.f,0.f};
      gemm_reg<false>(h0b[t & 1] + mb, Wd0b, Wd0b, acc0, acc0, aoff, boff);
      cell_epi<true,false>(acc0, c0s, bd0v, wxdv, xin, scr, wave, quad, l15, m0, 0.f, nullptr);
      drain_h(scr, h0b[(t+1) & 1], m0, col0, tid);
    }
    gbar(cnt, epoch);
    // phase B: dec layer1 + pred reduce
    if (n_blk == 0 && tid < 64)
      astoref(&P.preds[((t+1) & 1)*BATCH + m0 + tid], 0.f);   // recycle for step t+1
    {
      f32x4 acc1[4][2];
      #pragma unroll
      for (int i = 0; i < 4; ++i)
        #pragma unroll
        for (int j = 0; j < 2; ++j) acc1[i][j] = f32x4{0.f,0.f,0.f,0.f};
      gemm_reg<false>(h0b[(t+1) & 1] + mb, Wd1ib, Wd1ib, acc1, acc1, aoff, boff);
      gemm_reg<false>(h1b[t & 1] + mb,     Wd1hb, Wd1hb, acc1, acc1, aoff, boff);
      cell_epi<false,true>(acc1, c1s, bd1v, nullptr, nullptr, scr, wave, quad, l15, m0,
                           fcWv, P.preds + (t & 1)*BATCH);
      drain_h(scr, h1b[(t+1) & 1], m0, col0, tid);
    }
    gbar(cnt, epoch);
  }
  if (n_blk == 0 && tid < 64){
    const float pv = aloadf(&P.preds[((T_LEN-1) & 1)*BATCH + m0 + tid]);
    P.out[(size_t)(m0 + tid)*T_LEN + (T_LEN-1)] = pv + fcb;
  }
}

// ---------------- host launcher ----------------
extern "C" void kernel_launch(void* const* d_in, const int* in_sizes, int n_in,
                              void* d_out, int out_size, void* d_ws, size_t ws_size,
                              hipStream_t stream){
  const float* x     = (const float*)d_in[0];
  const float* eWih0 = (const float*)d_in[1];
  const float* eWhh0 = (const float*)d_in[2];
  const float* ebih0 = (const float*)d_in[3];
  const float* ebhh0 = (const float*)d_in[4];
  const float* eWih1 = (const float*)d_in[5];
  const float* eWhh1 = (const float*)d_in[6];
  const float* ebih1 = (const float*)d_in[7];
  const float* ebhh1 = (const float*)d_in[8];
  const float* dWih0 = (const float*)d_in[9];
  const float* dWhh0 = (const float*)d_in[10];
  const float* dbih0 = (const float*)d_in[11];
  const float* dbhh0 = (const float*)d_in[12];
  const float* dWih1 = (const float*)d_in[13];
  const float* dWhh1 = (const float*)d_in[14];
  const float* dbih1 = (const float*)d_in[15];
  const float* dbhh1 = (const float*)d_in[16];
  const float* fcW   = (const float*)d_in[17];
  const float* fcb   = (const float*)d_in[18];

  char* ws = (char*)d_ws;
  size_t off = 0;
  auto alloc = [&](size_t bytes)->char*{
    char* p = ws + off; off += (bytes + 255) & ~(size_t)255; return p;
  };
  u16* We0  = (u16*)alloc((size_t)2048*512*2);
  u16* We1i = (u16*)alloc((size_t)2048*512*2);
  u16* We1h = (u16*)alloc((size_t)2048*512*2);
  u16* Wd0  = (u16*)alloc((size_t)2048*512*2);
  u16* Wd1i = (u16*)alloc((size_t)2048*512*2);
  u16* Wd1h = (u16*)alloc((size_t)2048*512*2);
  char* zbase = ws + off;
  u16* h0buf = (u16*)alloc(2*HBUF*2);
  u16* h1buf = (u16*)alloc(2*HBUF*2);
  float* preds = (float*)alloc(2*BATCH*4);
  unsigned* gcnt = (unsigned*)alloc(32*32*4);
  size_t zbytes = (size_t)((ws + off) - zbase);
  float* be0 = (float*)alloc(2048*4);
  float* be1 = (float*)alloc(2048*4);
  float* bd0 = (float*)alloc(2048*4);
  float* bd1 = (float*)alloc(2048*4);
  float* wxe = (float*)alloc(2048*4);
  float* wxd = (float*)alloc(2048*4);

  hipMemsetAsync(zbase, 0, zbytes, stream);
  dim3 gw((2048*512)/256);
  k_reorder_w<<<gw,256,0,stream>>>(eWhh0, We0);
  k_reorder_w<<<gw,256,0,stream>>>(eWih1, We1i);
  k_reorder_w<<<gw,256,0,stream>>>(eWhh1, We1h);
  k_reorder_w<<<gw,256,0,stream>>>(dWhh0, Wd0);
  k_reorder_w<<<gw,256,0,stream>>>(dWih1, Wd1i);
  k_reorder_w<<<gw,256,0,stream>>>(dWhh1, Wd1h);
  k_prep_small<<<8,256,0,stream>>>(ebih0, ebhh0, be0, eWih0, wxe);
  k_prep_small<<<8,256,0,stream>>>(ebih1, ebhh1, be1, (const float*)nullptr, (float*)nullptr);
  k_prep_small<<<8,256,0,stream>>>(dbih0, dbhh0, bd0, dWih0, wxd);
  k_prep_small<<<8,256,0,stream>>>(dbih1, dbhh1, bd1, (const float*)nullptr, (float*)nullptr);

  Params P{ x, We0, We1i, We1h, Wd0, Wd1i, Wd1h,
            be0, be1, bd0, bd1, wxe, wxd, fcW, fcb,
            h0buf, h1buf, preds, gcnt, (float*)d_out };
  // plain launch, always (m-groups are independent: no grid-wide co-residency needed)
  lstm_main<<<dim3(NBLK), dim3(256), 0, stream>>>(P);
}

// Round 5
// 22734.441 us; speedup vs baseline: 2.0466x; 2.0466x over previous
//
#include <hip/hip_runtime.h>
#include <stdint.h>

typedef unsigned short u16;
typedef unsigned long long u64;
typedef __bf16 bf16x8 __attribute__((ext_vector_type(8)));
typedef float f32x4 __attribute__((ext_vector_type(4)));

#define S_LEN 288
#define T_LEN 144
#define HID   512
#define BATCH 2048
#define NBLK  256
#define THREADS 512
#define HBUF  ((size_t)BATCH * HID)

// LDS arena (u16 elems): two staged A tiles + h scratch
// A tile: 16 chunks, pitch 2056 elems (64 rows x 32 + 8 pad for bank rotation)
#define APITCH 2056
#define ATILE  (16*APITCH)          // 32896 elems
#define SCROFF (2*ATILE)            // scratch at 65792
#define ARENA_ELEMS (2*ATILE + 64*68)

__device__ __forceinline__ u16 f2bf(float f){
  unsigned u = __builtin_bit_cast(unsigned, f);
  u = u + 0x7fffu + ((u >> 16) & 1u);
  return (u16)(u >> 16);
}
__device__ __forceinline__ float sigf(float x){ return 1.0f/(1.0f + __expf(-x)); }
__device__ __forceinline__ float tanh_f(float x){ return 1.0f - 2.0f/(1.0f + __expf(2.0f*x)); }

// agent-scope (sc1): bypass per-XCD L2, coherent device-wide (replay-proven R2/R4)
__device__ __forceinline__ u64 aload64(const u16* p){
  return __hip_atomic_load((const u64*)p, __ATOMIC_RELAXED, __HIP_MEMORY_SCOPE_AGENT);
}
__device__ __forceinline__ float aloadf(const float* p){
  return __hip_atomic_load(p, __ATOMIC_RELAXED, __HIP_MEMORY_SCOPE_AGENT);
}
__device__ __forceinline__ void astore64(void* p, u64 v){
  __hip_atomic_store((u64*)p, v, __ATOMIC_RELAXED, __HIP_MEMORY_SCOPE_AGENT);
}
__device__ __forceinline__ void astoref(float* p, float v){
  __hip_atomic_store(p, v, __ATOMIC_RELAXED, __HIP_MEMORY_SCOPE_AGENT);
}

struct Params {
  const float* x;
  const u16 *We0, *We1i, *We1h, *Wd0, *Wd1i, *Wd1h;
  const float *be0, *be1, *bd0, *bd1, *wxe, *wxd, *fcW, *fcbp;
  u16 *h0buf, *h1buf;
  float* preds;
  unsigned* gcnt;
  float* out;
};

// ---------------- prep kernels ----------------
// orig row = gate*512 + hu  ->  new row = (hu>>3)*32 + gate*8 + (hu&7)
__global__ void k_reorder_w(const float* __restrict__ src, u16* __restrict__ dst){
  int idx  = blockIdx.x * 256 + threadIdx.x;
  int k    = idx & (HID-1);
  int orig = idx >> 9;
  int gate = orig >> 9, hu = orig & (HID-1);
  int nr   = ((hu >> 3) << 5) + (gate << 3) + (hu & 7);
  dst[(size_t)nr * HID + k] = f2bf(src[idx]);
}

__global__ void k_prep_small(const float* __restrict__ bih, const float* __restrict__ bhh,
                             float* __restrict__ bdst,
                             const float* __restrict__ wcol, float* __restrict__ wdst){
  int orig = blockIdx.x * 256 + threadIdx.x;
  int gate = orig >> 9, hu = orig & (HID-1);
  int nr   = ((hu >> 3) << 5) + (gate << 3) + (hu & 7);
  bdst[nr] = bih[orig] + bhh[orig];
  if (wcol) wdst[nr] = wcol[orig];
}

// ---------------- m-group barrier (8 blocks, own cacheline, R2-proven shape) ----------------
__device__ __forceinline__ void gbar(unsigned* cnt, unsigned& epoch){
  __syncthreads();
  ++epoch;
  if (threadIdx.x == 0){
    __hip_atomic_fetch_add(cnt, 1u, __ATOMIC_RELEASE, __HIP_MEMORY_SCOPE_AGENT);
    const unsigned tgt = epoch * 8u;
    while (__hip_atomic_load(cnt, __ATOMIC_RELAXED, __HIP_MEMORY_SCOPE_AGENT) < tgt)
      __builtin_amdgcn_s_sleep(1);
  }
  __syncthreads();
}

// ---------------- A-tile staging: one burst of sc1 loads -> LDS ----------------
// tile = 64 rows x 512 cols (u16).  8192 u64 units = 512 thr x 16.
// unit u = i*512 + tid: r = 4i + (tid>>7), c = (tid>>3)&15, q8 = tid&7  (global-coalesced)
__device__ __forceinline__ void stage1(const u16* __restrict__ Ag, u16* lA, int tid){
  const int rb = tid >> 7, c = (tid >> 3) & 15, q8 = tid & 7;
  const int s = q8 >> 1, hh = (q8 & 1) * 4;
  const size_t gb = (size_t)c*32 + q8*4;
  u64 v[16];
  #pragma unroll
  for (int i = 0; i < 16; ++i)
    v[i] = aload64(Ag + (size_t)(4*i + rb)*HID + gb);
  #pragma unroll
  for (int i = 0; i < 16; ++i){
    const int r = 4*i + rb;
    lA[c*APITCH + r*32 + ((s ^ ((r>>1)&3))<<3) + hh] = 0; // placate aliasing? no—overwritten below
    *(u64*)&lA[c*APITCH + r*32 + ((s ^ ((r>>1)&3))<<3) + hh] = v[i];
  }
}

// stage two tiles with overlapped load bursts (single latency exposure)
__device__ __forceinline__ void stage2(const u16* __restrict__ A0, const u16* __restrict__ A1,
                                       u16* lA0, u16* lA1, int tid){
  const int rb = tid >> 7, c = (tid >> 3) & 15, q8 = tid & 7;
  const int s = q8 >> 1, hh = (q8 & 1) * 4;
  const size_t gb = (size_t)c*32 + q8*4;
  u64 v0[16], v1[16];
  #pragma unroll
  for (int i = 0; i < 16; ++i) v0[i] = aload64(A0 + (size_t)(4*i + rb)*HID + gb);
  #pragma unroll
  for (int i = 0; i < 16; ++i) v1[i] = aload64(A1 + (size_t)(4*i + rb)*HID + gb);
  #pragma unroll
  for (int i = 0; i < 16; ++i){
    const int r = 4*i + rb;
    *(u64*)&lA0[c*APITCH + r*32 + ((s ^ ((r>>1)&3))<<3) + hh] = v0[i];
  }
  #pragma unroll
  for (int i = 0; i < 16; ++i){
    const int r = 4*i + rb;
    *(u64*)&lA1[c*APITCH + r*32 + ((s ^ ((r>>1)&3))<<3) + hh] = v1[i];
  }
}

// ---------------- K=512 GEMM from staged LDS A, B streamed w/ depth-3 prefetch ----------------
template<bool DUAL>
__device__ __forceinline__ void gemm_lds(
    const u16* lA, const u16* __restrict__ Bg, const u16* __restrict__ B2g,
    f32x4 (&acc)[4][2], f32x4 (&acc2)[4][2],
    const int (&aloff)[4], const int (&boff)[2])
{
  int4 bq[3][2], b2q[3][2];
  #pragma unroll
  for (int st = 0; st < 3; ++st)
    #pragma unroll
    for (int nf = 0; nf < 2; ++nf){
      bq[st][nf] = *(const int4*)(Bg + boff[nf] + st*32);
      if (DUAL) b2q[st][nf] = *(const int4*)(B2g + boff[nf] + st*32);
    }
  #pragma unroll
  for (int c = 0; c < 16; ++c){
    bf16x8 af[4];
    #pragma unroll
    for (int mf = 0; mf < 4; ++mf)
      af[mf] = *(const bf16x8*)&lA[c*APITCH + aloff[mf]];
    const int st = c % 3;
    #pragma unroll
    for (int mf = 0; mf < 4; ++mf)
      #pragma unroll
      for (int nf = 0; nf < 2; ++nf){
        acc[mf][nf] = __builtin_amdgcn_mfma_f32_16x16x32_bf16(
            af[mf], __builtin_bit_cast(bf16x8, bq[st][nf]), acc[mf][nf], 0, 0, 0);
        if (DUAL)
          acc2[mf][nf] = __builtin_amdgcn_mfma_f32_16x16x32_bf16(
              af[mf], __builtin_bit_cast(bf16x8, b2q[st][nf]), acc2[mf][nf], 0, 0, 0);
      }
    if (c < 13){
      #pragma unroll
      for (int nf = 0; nf < 2; ++nf){
        bq[st][nf] = *(const int4*)(Bg + boff[nf] + (c+3)*32);
        if (DUAL) b2q[st][nf] = *(const int4*)(B2g + boff[nf] + (c+3)*32);
      }
    }
  }
}

// ---------------- LSTM cell epilogue (R4-proven gate mapping) ----------------
// n-row (wave*32 + nf*16 + l15) -> gate nf*2+(l15>>3) of hu = n_blk*64 + wave*8 + (l15&7)
template<bool X0, bool PRED>
__device__ __forceinline__ void cell_epi(
    f32x4 (&acc)[4][2], float* cst, const float* bv, const float* wxv,
    const float* xin, u16* scr,
    int wave, int quad, int l15, int m0,
    float fcWv, float* predrow)
{
  const int hilane = l15 >> 3, hu7 = l15 & 7;
  #pragma unroll
  for (int mf = 0; mf < 4; ++mf){
    #pragma unroll
    for (int r = 0; r < 4; ++r){
      const float a0 = acc[mf][0][r], a1 = acc[mf][1][r];
      const float p0 = __shfl_xor(a0, 8), p1 = __shfl_xor(a1, 8);
      float gi = (hilane ? p0 : a0) + bv[0];
      float gf = (hilane ? a0 : p0) + bv[1];
      float gg = (hilane ? p1 : a1) + bv[2];
      float go = (hilane ? a1 : p1) + bv[3];
      if (X0){
        const float xt = xin[mf*4 + r];
        gi += xt*wxv[0]; gf += xt*wxv[1]; gg += xt*wxv[2]; go += xt*wxv[3];
      }
      const float c = sigf(gf)*cst[mf*4+r] + sigf(gi)*tanh_f(gg);
      cst[mf*4+r] = c;
      const float h = sigf(go)*tanh_f(c);
      if (!hilane) scr[(mf*16 + quad*4 + r)*68 + wave*8 + hu7] = f2bf(h);
      if (PRED){
        float v = hilane ? 0.f : h*fcWv;
        v += __shfl_xor(v, 1); v += __shfl_xor(v, 2);
        v += __shfl_xor(v, 4); v += __shfl_xor(v, 8);
        if (l15 == 0) atomicAdd(&predrow[m0 + mf*16 + quad*4 + r], v);
      }
    }
  }
}

// drain scratch (64 rows x 64 cols, pitch 68) -> global h (sc1, 16B/thread)
__device__ __forceinline__ void drain_h(const u16* scr, u16* hdst, int m0, int col0, int tid){
  __syncthreads();
  const int row = tid >> 3, q = tid & 7;
  const u64* s = (const u64*)(scr + row*68 + q*8);
  const u64 lo = s[0], hi = s[1];
  u64* d = (u64*)(hdst + (size_t)(m0+row)*HID + col0 + q*8);
  astore64(d, lo);
  astore64(d+1, hi);
  __syncthreads();
}

// ---------------- persistent main kernel ----------------
__global__ __launch_bounds__(THREADS, 1) void lstm_main(Params P){
  const int tid   = threadIdx.x;
  const int bx    = blockIdx.x;
  const int n_blk = bx & 7;            // same n-slice per XCD (heuristic; correctness-neutral)
  const int m_blk = bx >> 3;           // 0..31; m-group = 8 consecutive bx
  const int m0 = m_blk * 64;
  const int wave = tid >> 6, lane = tid & 63;
  const int l15 = lane & 15, quad = lane >> 4;
  const int hu7 = l15 & 7;
  const int hu = n_blk*64 + wave*8 + hu7;
  const int col0 = n_blk*64;

  extern __shared__ u16 dummy_unused[];   // (not used; static arena below)
  __shared__ u16 arena[ARENA_ELEMS];      // 140 KB: gfx950 LDS = 160 KB
  u16* lA0 = arena;
  u16* lA1 = arena + ATILE;
  u16* scr = arena + SCROFF;

  unsigned* cnt = P.gcnt + m_blk*32;

  // A-fragment LDS offsets (row = mf*16+l15, 16B slot = quad^swz(row))
  int aloff[4], boff[2];
  #pragma unroll
  for (int mf = 0; mf < 4; ++mf){
    const int r = mf*16 + l15;
    aloff[mf] = r*32 + ((quad ^ ((r>>1)&3))<<3);
  }
  #pragma unroll
  for (int nf = 0; nf < 2; ++nf)
    boff[nf] = (wave*32 + nf*16 + l15)*HID + quad*8;

  float c0s[16], c1s[16];
  #pragma unroll
  for (int i = 0; i < 16; ++i){ c0s[i] = 0.f; c1s[i] = 0.f; }

  float be0v[4], be1v[4], bd0v[4], bd1v[4], wxev[4], wxdv[4];
  #pragma unroll
  for (int g = 0; g < 4; ++g){
    const int col = n_blk*256 + wave*32 + g*8 + hu7;
    be0v[g] = P.be0[col]; be1v[g] = P.be1[col];
    bd0v[g] = P.bd0[col]; bd1v[g] = P.bd1[col];
    wxev[g] = P.wxe[col]; wxdv[g] = P.wxd[col];
  }
  const float fcWv = P.fcW[hu];
  const float fcb  = P.fcbp[0];

  const size_t nb = (size_t)(n_blk*256) * HID;
  const u16* We0b  = P.We0  + nb;
  const u16* We1ib = P.We1i + nb;
  const u16* We1hb = P.We1h + nb;
  const u16* Wd0b  = P.Wd0  + nb;
  const u16* Wd1ib = P.Wd1i + nb;
  const u16* Wd1hb = P.Wd1h + nb;
  const size_t mb = (size_t)m0 * HID;
  u16* h0b[2] = { P.h0buf, P.h0buf + HBUF };
  u16* h1b[2] = { P.h1buf, P.h1buf + HBUF };

  unsigned epoch = 0;

  // ===== encoder: phase p runs layer0(t=p) and layer1(t=p-1) =====
  for (int p = 0; p <= S_LEN; ++p){
    stage2(h0b[p & 1] + mb, h1b[(p+1) & 1] + mb, lA0, lA1, tid);
    __syncthreads();

    f32x4 acc0[4][2], acc1[4][2];
    #pragma unroll
    for (int i = 0; i < 4; ++i)
      #pragma unroll
      for (int j = 0; j < 2; ++j){ acc0[i][j] = f32x4{0.f,0.f,0.f,0.f}; acc1[i][j] = f32x4{0.f,0.f,0.f,0.f}; }

    // seg1: A = h0(p-1): layer0 recurrence + layer1 input (dual B)
    gemm_lds<true >(lA0, We0b, We1ib, acc0, acc1, aloff, boff);
    // seg2: A = h1(p-2): layer1 recurrence
    gemm_lds<false>(lA1, We1hb, We1hb, acc1, acc1, aloff, boff);

    if (p < S_LEN){
      float xin[16];
      #pragma unroll
      for (int mf = 0; mf < 4; ++mf)
        #pragma unroll
        for (int r = 0; r < 4; ++r)
          xin[mf*4+r] = P.x[(size_t)(m0 + mf*16 + quad*4 + r)*S_LEN + p];
      cell_epi<true,false>(acc0, c0s, be0v, wxev, xin, scr, wave, quad, l15, m0, 0.f, nullptr);
      drain_h(scr, h0b[(p+1) & 1], m0, col0, tid);
    }
    if (p >= 1){
      cell_epi<false,false>(acc1, c1s, be1v, nullptr, nullptr, scr, wave, quad, l15, m0, 0.f, nullptr);
      drain_h(scr, h1b[p & 1], m0, col0, tid);
    }
    gbar(cnt, epoch);
  }

  // ===== decoder: 2 phases per step (pred feedback) =====
  for (int t = 0; t < T_LEN; ++t){
    if (t > 0 && n_blk == 0 && tid < 64){
      const float pv = aloadf(&P.preds[((t+1) & 1)*BATCH + m0 + tid]);
      P.out[(size_t)(m0 + tid)*T_LEN + (t-1)] = pv + fcb;
    }
    { // phase A: dec layer0
      stage1(h0b[t & 1] + mb, lA0, tid);
      __syncthreads();
      f32x4 acc0[4][2];
      #pragma unroll
      for (int i = 0; i < 4; ++i)
        #pragma unroll
        for (int j = 0; j < 2; ++j) acc0[i][j] = f32x4{0.f,0.f,0.f,0.f};
      gemm_lds<false>(lA0, Wd0b, Wd0b, acc0, acc0, aloff, boff);
      float xin[16];
      #pragma unroll
      for (int mf = 0; mf < 4; ++mf)
        #pragma unroll
        for (int r = 0; r < 4; ++r){
          const int b = m0 + mf*16 + quad*4 + r;
          xin[mf*4+r] = (t == 0) ? P.x[(size_t)b*S_LEN + (S_LEN-1)]
                                 : (aloadf(&P.preds[((t+1) & 1)*BATCH + b]) + fcb);
        }
      cell_epi<true,false>(acc0, c0s, bd0v, wxdv, xin, scr, wave, quad, l15, m0, 0.f, nullptr);
      drain_h(scr, h0b[(t+1) & 1], m0, col0, tid);
    }
    gbar(cnt, epoch);
    // phase B: dec layer1 + pred reduce
    if (n_blk == 0 && tid < 64)
      astoref(&P.preds[((t+1) & 1)*BATCH + m0 + tid], 0.f);   // recycle for step t+1
    {
      stage2(h0b[(t+1) & 1] + mb, h1b[t & 1] + mb, lA0, lA1, tid);
      __syncthreads();
      f32x4 acc1[4][2];
      #pragma unroll
      for (int i = 0; i < 4; ++i)
        #pragma unroll
        for (int j = 0; j < 2; ++j) acc1[i][j] = f32x4{0.f,0.f,0.f,0.f};
      gemm_lds<false>(lA0, Wd1ib, Wd1ib, acc1, acc1, aloff, boff);
      gemm_lds<false>(lA1, Wd1hb, Wd1hb, acc1, acc1, aloff, boff);
      cell_epi<false,true>(acc1, c1s, bd1v, nullptr, nullptr, scr, wave, quad, l15, m0,
                           fcWv, P.preds + (t & 1)*BATCH);
      drain_h(scr, h1b[(t+1) & 1], m0, col0, tid);
    }
    gbar(cnt, epoch);
  }
  if (n_blk == 0 && tid < 64){
    const float pv = aloadf(&P.preds[((T_LEN-1) & 1)*BATCH + m0 + tid]);
    P.out[(size_t)(m0 + tid)*T_LEN + (T_LEN-1)] = pv + fcb;
  }
}

// ---------------- host launcher ----------------
extern "C" void kernel_launch(void* const* d_in, const int* in_sizes, int n_in,
                              void* d_out, int out_size, void* d_ws, size_t ws_size,
                              hipStream_t stream){
  const float* x     = (const float*)d_in[0];
  const float* eWih0 = (const float*)d_in[1];
  const float* eWhh0 = (const float*)d_in[2];
  const float* ebih0 = (const float*)d_in[3];
  const float* ebhh0 = (const float*)d_in[4];
  const float* eWih1 = (const float*)d_in[5];
  const float* eWhh1 = (const float*)d_in[6];
  const float* ebih1 = (const float*)d_in[7];
  const float* ebhh1 = (const float*)d_in[8];
  const float* dWih0 = (const float*)d_in[9];
  const float* dWhh0 = (const float*)d_in[10];
  const float* dbih0 = (const float*)d_in[11];
  const float* dbhh0 = (const float*)d_in[12];
  const float* dWih1 = (const float*)d_in[13];
  const float* dWhh1 = (const float*)d_in[14];
  const float* dbih1 = (const float*)d_in[15];
  const float* dbhh1 = (const float*)d_in[16];
  const float* fcW   = (const float*)d_in[17];
  const float* fcb   = (const float*)d_in[18];

  char* ws = (char*)d_ws;
  size_t off = 0;
  auto alloc = [&](size_t bytes)->char*{
    char* p = ws + off; off += (bytes + 255) & ~(size_t)255; return p;
  };
  u16* We0  = (u16*)alloc((size_t)2048*512*2);
  u16* We1i = (u16*)alloc((size_t)2048*512*2);
  u16* We1h = (u16*)alloc((size_t)2048*512*2);
  u16* Wd0  = (u16*)alloc((size_t)2048*512*2);
  u16* Wd1i = (u16*)alloc((size_t)2048*512*2);
  u16* Wd1h = (u16*)alloc((size_t)2048*512*2);
  char* zbase = ws + off;
  u16* h0buf = (u16*)alloc(2*HBUF*2);
  u16* h1buf = (u16*)alloc(2*HBUF*2);
  float* preds = (float*)alloc(2*BATCH*4);
  unsigned* gcnt = (unsigned*)alloc(32*32*4);
  size_t zbytes = (size_t)((ws + off) - zbase);
  float* be0 = (float*)alloc(2048*4);
  float* be1 = (float*)alloc(2048*4);
  float* bd0 = (float*)alloc(2048*4);
  float* bd1 = (float*)alloc(2048*4);
  float* wxe = (float*)alloc(2048*4);
  float* wxd = (float*)alloc(2048*4);

  hipMemsetAsync(zbase, 0, zbytes, stream);
  dim3 gw((2048*512)/256);
  k_reorder_w<<<gw,256,0,stream>>>(eWhh0, We0);
  k_reorder_w<<<gw,256,0,stream>>>(eWih1, We1i);
  k_reorder_w<<<gw,256,0,stream>>>(eWhh1, We1h);
  k_reorder_w<<<gw,256,0,stream>>>(dWhh0, Wd0);
  k_reorder_w<<<gw,256,0,stream>>>(dWih1, Wd1i);
  k_reorder_w<<<gw,256,0,stream>>>(dWhh1, Wd1h);
  k_prep_small<<<8,256,0,stream>>>(ebih0, ebhh0, be0, eWih0, wxe);
  k_prep_small<<<8,256,0,stream>>>(ebih1, ebhh1, be1, (const float*)nullptr, (float*)nullptr);
  k_prep_small<<<8,256,0,stream>>>(dbih0, dbhh0, bd0, dWih0, wxd);
  k_prep_small<<<8,256,0,stream>>>(dbih1, dbhh1, bd1, (const float*)nullptr, (float*)nullptr);

  Params P{ x, We0, We1i, We1h, Wd0, Wd1i, Wd1h,
            be0, be1, bd0, bd1, wxe, wxd, fcW, fcb,
            h0buf, h1buf, preds, gcnt, (float*)d_out };
  // plain launch: 256 blocks at 1/CU, m-groups independent
  lstm_main<<<dim3(NBLK), dim3(THREADS), 0, stream>>>(P);
}